// Round 3
// baseline (171.422 us; speedup 1.0000x reference)
//
#include <hip/hip_runtime.h>
#include <hip/hip_bf16.h>

typedef unsigned short u16;
typedef __bf16 bf16x8 __attribute__((ext_vector_type(8)));
typedef __bf16 bf16x4 __attribute__((ext_vector_type(4)));
typedef float f32x4 __attribute__((ext_vector_type(4)));
typedef unsigned int uint32x2 __attribute__((ext_vector_type(2)));

#define MFMA16(a, b, c) __builtin_amdgcn_mfma_f32_16x16x32_bf16(a, b, c, 0, 0, 0)

// exp(z/8) = exp2(z * log2(e)/8); folded into fkT at projection time.
#define FK_SCALE 0.1803368801111204f  // 0.125 * log2(e)

#define NSPLIT 4

// ---------------------------------------------------------------------------
// Projections: fkeys/fvals/hkeys = W @ src + b, output bf16.
//   fkT[b][l][64]  (k contiguous, PRE-SCALED by FK_SCALE)
//   hkT[b][q][64]  (k contiguous)
//   fv [b][64][l]  (l contiguous)
// grid: (16, B, 12)  z = proj*4 + kquarter  (16 k-rows per block).
// Chunked f-accumulation: xc[16]+acc[16] only -> ~56 VGPRs, NO scratch spill
// (the round-1/2 versions held x[128] in registers and spilled to scratch,
//  which is why proj burned ~80 us for 0.8 GFLOP).
// ---------------------------------------------------------------------------
__global__ __launch_bounds__(256) void proj_kernel(
    const float* __restrict__ field, const float* __restrict__ query,
    const float* __restrict__ Wfk, const float* __restrict__ bfk,
    const float* __restrict__ Wfv, const float* __restrict__ bfv,
    const float* __restrict__ Wqk, const float* __restrict__ bqk,
    u16* __restrict__ fkT, u16* __restrict__ fvp, u16* __restrict__ hkT) {
  const int l = blockIdx.x * 256 + threadIdx.x;
  const int b = blockIdx.y;
  const int z = blockIdx.z;
  const int proj = z >> 2;        // 0=fk, 1=fv, 2=hk
  const int k0 = (z & 3) * 16;

  const float* src  = (proj == 2) ? query : field;
  const float* W    = (proj == 0) ? Wfk : (proj == 1) ? Wfv : Wqk;
  const float* bias = (proj == 0) ? bfk : (proj == 1) ? bfv : bqk;

  const float* sp = src + (size_t)b * 128 * 4096 + l;

  float acc[16];
#pragma unroll
  for (int i = 0; i < 16; ++i) acc[i] = bias[k0 + i];

#pragma unroll 1
  for (int fc = 0; fc < 128; fc += 16) {
    float xc[16];
#pragma unroll
    for (int j = 0; j < 16; ++j) xc[j] = sp[(size_t)(fc + j) * 4096];
#pragma unroll
    for (int i = 0; i < 16; ++i) {
      const float* wr = W + (size_t)(k0 + i) * 128 + fc;
      float a = acc[i];
#pragma unroll
      for (int j = 0; j < 16; ++j) a = fmaf(wr[j], xc[j], a);
      acc[i] = a;
    }
  }

  if (proj == 1) {
#pragma unroll
    for (int i = 0; i < 16; ++i) {
      __bf16 h = (__bf16)acc[i];
      fvp[((size_t)(b * 64 + k0 + i)) * 4096 + l] = __builtin_bit_cast(u16, h);
    }
  } else {
    const float cs = (proj == 0) ? FK_SCALE : 1.0f;
    u16* dst = ((proj == 0) ? fkT : hkT) + ((size_t)(b * 4096 + l)) * 64 + k0;
#pragma unroll
    for (int g = 0; g < 2; ++g) {
      bf16x8 o;
#pragma unroll
      for (int j = 0; j < 8; ++j) o[j] = (__bf16)(acc[g * 8 + j] * cs);
      *reinterpret_cast<bf16x8*>(dst + g * 8) = o;
    }
  }
}

// ---------------------------------------------------------------------------
// Attention: per (qtile of 64, b, l-split of 1024). 16 iters of 64 l.
//   S'[l][q] = fkT . hk   (scale pre-folded; hk frags persistent in regs)
//   P = exp2(S') -> bf16 -> LDS P_T[q][l], XOR-swizzled, DOUBLE-BUFFERED
//   Y[v][q] += fv . P     (waves = 32x32 quadrants)
// One barrier per iteration; fv frags issued at iter top (latency hidden
// under S+exp+LDS+barrier); fk frags prefetched one iteration ahead.
// ---------------------------------------------------------------------------
__global__ __launch_bounds__(256, 4) void attn_kernel(
    const u16* __restrict__ fkT, const u16* __restrict__ hkT,
    const u16* __restrict__ fvp, float* __restrict__ Ynum,
    float* __restrict__ den) {
  constexpr int LL = 4096, DD = 64, NITER = (LL / NSPLIT) / 64;
  const int tid = threadIdx.x;
  const int w = tid >> 6;
  const int lane = tid & 63;
  const int q15 = lane & 15;
  const int quad = lane >> 4;
  const int qtile = blockIdx.x;
  const int b = blockIdx.y;
  const int split = blockIdx.z;
  const int q0 = qtile * 64;
  const int l0base = split * (LL / NSPLIT);
  const int sw = (q15 & 7) << 1;  // XOR swizzle (8B-block granularity)

  __shared__ __align__(16) u16 sP[2][64 * 64];  // P_T[q][l], swizzled, dbuf
  __shared__ float sDred[4][64];

  // hk B-fragments, persistent: B[k][n=q], n=lane&15, k=quad*8+j
  bf16x8 hkf[4][2];
#pragma unroll
  for (int j = 0; j < 4; ++j)
#pragma unroll
    for (int ks = 0; ks < 2; ++ks)
      hkf[j][ks] = *reinterpret_cast<const bf16x8*>(
          hkT + ((size_t)(b * LL + q0 + j * 16 + q15)) * DD + ks * 32 + quad * 8);

  f32x4 Yacc[2][2];
#pragma unroll
  for (int mm = 0; mm < 2; ++mm)
#pragma unroll
    for (int nn = 0; nn < 2; ++nn) Yacc[mm][nn] = (f32x4){0.f, 0.f, 0.f, 0.f};
  float dsum[4] = {0.f, 0.f, 0.f, 0.f};

  const int m0y = (w & 1) * 32;   // v quadrant
  const int n0y = (w >> 1) * 32;  // q quadrant

  const u16* fkBase = fkT + ((size_t)(b * LL + w * 16 + q15)) * DD + quad * 8;
  const u16* fvBase0 =
      fvp + ((size_t)(b * DD + m0y + q15)) * LL + quad * 8;
  const u16* fvBase1 = fvBase0 + (size_t)16 * LL;

  // preload fk fragments for it=0
  bf16x8 fkf[2];
#pragma unroll
  for (int ks = 0; ks < 2; ++ks)
    fkf[ks] = *reinterpret_cast<const bf16x8*>(
        fkBase + (size_t)l0base * DD + ks * 32);

#pragma unroll 2
  for (int it = 0; it < NITER; ++it) {
    const int l0 = l0base + it * 64;

    // --- early-issue PV fv-fragments (consumed after the barrier) ---
    bf16x8 af[2][2];
#pragma unroll
    for (int ks = 0; ks < 2; ++ks) {
      af[0][ks] = *reinterpret_cast<const bf16x8*>(fvBase0 + l0 + ks * 32);
      af[1][ks] = *reinterpret_cast<const bf16x8*>(fvBase1 + l0 + ks * 32);
    }
    // --- prefetch next iteration's fk fragments ---
    bf16x8 fkn[2];
    if (it + 1 < NITER) {
#pragma unroll
      for (int ks = 0; ks < 2; ++ks)
        fkn[ks] = *reinterpret_cast<const bf16x8*>(
            fkBase + (size_t)(l0 + 64) * DD + ks * 32);
    }

    // --- S' = fk^T . hk for this wave's 16-row strip ---
    f32x4 accS[4];
#pragma unroll
    for (int j = 0; j < 4; ++j) accS[j] = (f32x4){0.f, 0.f, 0.f, 0.f};
#pragma unroll
    for (int ks = 0; ks < 2; ++ks)
#pragma unroll
      for (int j = 0; j < 4; ++j) accS[j] = MFMA16(fkf[ks], hkf[j][ks], accS[j]);

    // --- P = exp2(S') -> bf16 -> LDS transposed, swizzled (buf it&1) ---
    u16* sPb = sP[it & 1];
#pragma unroll
    for (int j = 0; j < 4; ++j) {
      bf16x4 pk;
      float ds = 0.f;
#pragma unroll
      for (int r = 0; r < 4; ++r) {
        float e = __builtin_amdgcn_exp2f(accS[j][r]);
        pk[r] = (__bf16)e;
        ds += e;
      }
      dsum[j] += ds;
      const int blk = (w * 4 + quad) ^ sw;
      *reinterpret_cast<uint32x2*>(&sPb[(j * 16 + q15) * 64 + blk * 4]) =
          __builtin_bit_cast(uint32x2, pk);
    }
    __syncthreads();  // sPb visible; prior-iter reads of this buf long done

    // --- Y += fv . P  (wave quadrant m0y x n0y, 32x32) ---
#pragma unroll
    for (int ks = 0; ks < 2; ++ks) {
      bf16x8 bfr[2];
#pragma unroll
      for (int nn = 0; nn < 2; ++nn) {
        const int b0 = (ks * 8 + quad * 2) ^ sw;
        bfr[nn] = *reinterpret_cast<const bf16x8*>(
            &sPb[(n0y + nn * 16 + q15) * 64 + b0 * 4]);
      }
#pragma unroll
      for (int mm = 0; mm < 2; ++mm)
#pragma unroll
        for (int nn = 0; nn < 2; ++nn)
          Yacc[mm][nn] = MFMA16(af[mm][ks], bfr[nn], Yacc[mm][nn]);
    }

    fkf[0] = fkn[0];
    fkf[1] = fkn[1];
  }

  // --- denom: reduce across quads (strip rows), then across waves ---
#pragma unroll
  for (int j = 0; j < 4; ++j) {
    float d = dsum[j];
    d += __shfl_xor(d, 16, 64);
    d += __shfl_xor(d, 32, 64);
    dsum[j] = d;
  }
  if (quad == 0) {
#pragma unroll
    for (int j = 0; j < 4; ++j) sDred[w][j * 16 + q15] = dsum[j];
  }
  __syncthreads();

  const size_t slot = ((size_t)split * 4 + b) * 64 + qtile;
  if (tid < 64) {
    den[slot * 64 + tid] =
        sDred[0][tid] + sDred[1][tid] + sDred[2][tid] + sDred[3][tid];
  }

  float* Yo = Ynum + slot * 4096;
#pragma unroll
  for (int mm = 0; mm < 2; ++mm)
#pragma unroll
    for (int nn = 0; nn < 2; ++nn)
#pragma unroll
      for (int r = 0; r < 4; ++r) {
        const int v = m0y + mm * 16 + quad * 4 + r;
        const int ql = n0y + nn * 16 + q15;
        Yo[v * 64 + ql] = Yacc[mm][nn][r];
      }
}

// ---------------------------------------------------------------------------
// Combine the NSPLIT l-splits and normalize. out[b][v][q], 1M elements.
// ---------------------------------------------------------------------------
__global__ __launch_bounds__(256) void combine_kernel(
    const float* __restrict__ Yn, const float* __restrict__ dn,
    float* __restrict__ out) {
  const int idx = blockIdx.x * 256 + threadIdx.x;
  const int q = idx & 4095;
  const int v = (idx >> 12) & 63;
  const int b = idx >> 18;
  const int qt = q >> 6, ql = q & 63;
  float num = 0.f, d = 1e-16f;
#pragma unroll
  for (int s = 0; s < NSPLIT; ++s) {
    const size_t slot = ((size_t)s * 4 + b) * 64 + qt;
    num += Yn[slot * 4096 + v * 64 + ql];
    d += dn[slot * 64 + ql];
  }
  out[idx] = num / d;
}

extern "C" void kernel_launch(void* const* d_in, const int* in_sizes, int n_in,
                              void* d_out, int out_size, void* d_ws,
                              size_t ws_size, hipStream_t stream) {
  const float* field = (const float*)d_in[0];
  const float* query = (const float*)d_in[1];
  const float* Wfk = (const float*)d_in[2];
  const float* bfk = (const float*)d_in[3];
  const float* Wfv = (const float*)d_in[4];
  const float* bfv = (const float*)d_in[5];
  const float* Wqk = (const float*)d_in[6];
  const float* bqk = (const float*)d_in[7];
  float* out = (float*)d_out;

  char* ws = (char*)d_ws;
  u16* fkT = (u16*)(ws);                       // 2 MB   [B][L][64] bf16 (scaled)
  u16* hkT = (u16*)(ws + (2ull << 20));        // 2 MB   [B][L][64] bf16
  u16* fvp = (u16*)(ws + (4ull << 20));        // 2 MB   [B][64][L] bf16
  float* Ynum = (float*)(ws + (6ull << 20));   // 16 MB  [4][B][64qt][64v][64q]
  float* den = (float*)(ws + (22ull << 20));   // 256 KB [4][B][64qt][64q]

  proj_kernel<<<dim3(16, 4, 12), 256, 0, stream>>>(field, query, Wfk, bfk, Wfv,
                                                   bfv, Wqk, bqk, fkT, fvp, hkT);
  attn_kernel<<<dim3(64, 4, NSPLIT), 256, 0, stream>>>(fkT, hkT, fvp, Ynum, den);
  combine_kernel<<<dim3(4096), 256, 0, stream>>>(Ynum, den, out);
}